// Round 5
// baseline (2026.136 us; speedup 1.0000x reference)
//
#include <hip/hip_runtime.h>

// ---------------- workspace layout (float offsets) ----------------
#define WS_SEQ      0LL          // [3][16384][128]
#define WS_XGGRU    6291456LL    // [6][16384][192]
#define WS_X        0LL          // [3][16384][128]
#define WS_TSTEP    18874368LL   // [16384][384]
#define WS_S        6291456LL    // [192][65536] scores (3 pairs x 64 batch)
#define WS_XGLSTM   0LL          // [2][16384][512]
#define WS_SF       16777216LL   // [16384][256]
#define WS_XGRGN    0LL          // [2][16384][384]
#define WS_OUT0     20971520LL   // [2][64][128]

__device__ __forceinline__ float sigf(float x) { return 1.f / (1.f + __expf(-x)); }
// readlane: lane index MUST be compile-time uniform (unrolled loops only)
__device__ __forceinline__ float rl(float v, int i) {
    return __int_as_float(__builtin_amdgcn_readlane(__float_as_int(v), i));
}

// ---------------- shared fp32 GEMM body: 64x64 tile, 1 wave, 8x8 micro -------
__device__ __forceinline__ void gemm_body(
    const float* __restrict__ Ab, int lda, const int* __restrict__ idx,
    const float* __restrict__ Wb, int wld, int wtrans,
    const float* __restrict__ bb,
    float* __restrict__ Cb, int ldc,
    int K, float alpha, int accum)
{
    int m0 = blockIdx.y * 64, n0 = blockIdx.x * 64;
    int t = threadIdx.x;
    int tx = t & 7, ty = t >> 3;

    __shared__ __align__(16) float As[16][68];
    __shared__ __align__(16) float Ws[16][68];

    float acc[8][8];
#pragma unroll
    for (int i = 0; i < 8; ++i)
#pragma unroll
        for (int j = 0; j < 8; ++j) acc[i][j] = 0.f;

    long long arow[4];
#pragma unroll
    for (int i = 0; i < 4; ++i) {
        int m = (t + i * 64) >> 2;
        arow[i] = idx ? (long long)idx[m0 + m] : (long long)(m0 + m);
    }
    const bool a_vec = ((lda & 3) == 0);

    for (int k0 = 0; k0 < K; k0 += 16) {
#pragma unroll
        for (int i = 0; i < 4; ++i) {
            int j = t + i * 64;
            int m = j >> 2, kq = j & 3;
            int kk = k0 + kq * 4;
            const float* p = Ab + arow[i] * (long long)lda + kk;
            float4 v = {0.f, 0.f, 0.f, 0.f};
            if (a_vec && kk + 3 < K) {
                v = *(const float4*)p;
            } else {
                if (kk + 0 < K) v.x = p[0];
                if (kk + 1 < K) v.y = p[1];
                if (kk + 2 < K) v.z = p[2];
                if (kk + 3 < K) v.w = p[3];
            }
            As[kq * 4 + 0][m] = v.x; As[kq * 4 + 1][m] = v.y;
            As[kq * 4 + 2][m] = v.z; As[kq * 4 + 3][m] = v.w;
        }
        if (!wtrans) {
#pragma unroll
            for (int i = 0; i < 4; ++i) {
                int j = t + i * 64;
                int k = j >> 4, nq = j & 15;
                float4 v = {0.f, 0.f, 0.f, 0.f};
                if (k0 + k < K)
                    v = *(const float4*)(Wb + (long long)(k0 + k) * wld + n0 + nq * 4);
                *(float4*)&Ws[k][nq * 4] = v;
            }
        } else {
#pragma unroll
            for (int i = 0; i < 4; ++i) {
                int j = t + i * 64;
                int n = j >> 2, kq = j & 3;
                int kk = k0 + kq * 4;
                const float* p = Wb + (long long)(n0 + n) * wld + kk;
                float4 v = {0.f, 0.f, 0.f, 0.f};
                if (kk + 3 < K) v = *(const float4*)p;
                else {
                    if (kk + 0 < K) v.x = p[0];
                    if (kk + 1 < K) v.y = p[1];
                    if (kk + 2 < K) v.z = p[2];
                    if (kk + 3 < K) v.w = p[3];
                }
                Ws[kq * 4 + 0][n] = v.x; Ws[kq * 4 + 1][n] = v.y;
                Ws[kq * 4 + 2][n] = v.z; Ws[kq * 4 + 3][n] = v.w;
            }
        }
        __syncthreads();
#pragma unroll
        for (int k = 0; k < 16; ++k) {
            float4 a0 = *(const float4*)&As[k][ty * 8];
            float4 a1 = *(const float4*)&As[k][ty * 8 + 4];
            float4 b0 = *(const float4*)&Ws[k][tx * 8];
            float4 b1 = *(const float4*)&Ws[k][tx * 8 + 4];
            float av[8] = {a0.x, a0.y, a0.z, a0.w, a1.x, a1.y, a1.z, a1.w};
            float bv[8] = {b0.x, b0.y, b0.z, b0.w, b1.x, b1.y, b1.z, b1.w};
#pragma unroll
            for (int i = 0; i < 8; ++i)
#pragma unroll
                for (int j = 0; j < 8; ++j)
                    acc[i][j] = fmaf(av[i], bv[j], acc[i][j]);
        }
        __syncthreads();
    }

#pragma unroll
    for (int i = 0; i < 8; ++i) {
        long long gm = m0 + ty * 8 + i;
#pragma unroll
        for (int jq = 0; jq < 2; ++jq) {
            float* cp = Cb + gm * ldc + n0 + tx * 8 + jq * 4;
            float4 v;
            v.x = alpha * acc[i][jq * 4 + 0]; v.y = alpha * acc[i][jq * 4 + 1];
            v.z = alpha * acc[i][jq * 4 + 2]; v.w = alpha * acc[i][jq * 4 + 3];
            if (bb) {
                const float* bp = bb + n0 + tx * 8 + jq * 4;
                v.x += bp[0]; v.y += bp[1]; v.z += bp[2]; v.w += bp[3];
            }
            if (accum) {
                float4 o = *(const float4*)cp;
                v.x += o.x; v.y += o.y; v.z += o.z; v.w += o.w;
            }
            *(float4*)cp = v;
        }
    }
}

// ---------------- generic GEMM launcher-kernel ----------------
__global__ __launch_bounds__(64) void gemm_k(
    const float* __restrict__ A, long long a_z, int a_zdiv, int lda,
    const int* __restrict__ idx,
    const float* __restrict__ W, long long w_z, int wld, int wtrans,
    const float* __restrict__ bias, int bias_z,
    float* __restrict__ C, long long c_z, int ldc,
    int K, float alpha, int accum)
{
    int z = blockIdx.z;
    gemm_body(A + (long long)(z / a_zdiv) * a_z, lda, idx,
              W + (long long)z * w_z, wld, wtrans,
              bias ? bias + (long long)z * bias_z : nullptr,
              C + (long long)z * c_z, ldc, K, alpha, accum);
}

// ---------------- batched attention score: S[z] = scale * q_b @ kv_b^T ------
__global__ __launch_bounds__(64) void att_score_k(
    const float* __restrict__ X, float* __restrict__ S,
    int q0, int q1, int q2, int k0, int k1, int k2)
{
    int z = blockIdx.z;
    int pair = z >> 6, b = z & 63;
    int qi = pair == 0 ? q0 : (pair == 1 ? q1 : q2);
    int ki = pair == 0 ? k0 : (pair == 1 ? k1 : k2);
    gemm_body(X + (long long)qi * 2097152 + (long long)b * 32768, 128, nullptr,
              X + (long long)ki * 2097152 + (long long)b * 32768, 128, 1,
              nullptr,
              S + (long long)z * 65536, 256, 128, 0.08838834764831845f, 0);
}

// ---------------- batched attention apply: tstep_slice += P_b @ kv_b --------
__global__ __launch_bounds__(64) void att_apply_k(
    const float* __restrict__ S, const float* __restrict__ X,
    float* __restrict__ tstep,
    int q0, int q1, int q2, int k0, int k1, int k2)
{
    int z = blockIdx.z;
    int pair = z >> 6, b = z & 63;
    int qi = pair == 0 ? q0 : (pair == 1 ? q1 : q2);
    int ki = pair == 0 ? k0 : (pair == 1 ? k1 : k2);
    gemm_body(S + (long long)z * 65536, 256, nullptr,
              X + (long long)ki * 2097152 + (long long)b * 32768, 128, 0,
              nullptr,
              tstep + (long long)qi * 128 + (long long)b * 98304, 384,
              256, 1.f, 1);
}

// ---------------- tstep init ----------------
__global__ __launch_bounds__(256) void copy_tstep_k(const float* __restrict__ x,
                                                    float* __restrict__ tstep)
{
    int o = blockIdx.x * 256 + threadIdx.x;
    int c = o % 384;
    int row = o / 384;
    int m = c >> 7, cc = c & 127;
    tstep[o] = x[(long long)m * 2097152 + (long long)row * 128 + cc];
}

// ---------------- softmax over rows of 256 (one wave per row) ----------------
__global__ __launch_bounds__(256) void softmax_k(float* __restrict__ S)
{
    int wave = threadIdx.x >> 6, lane = threadIdx.x & 63;
    int row = blockIdx.x * 4 + wave;
    float* p = S + (long long)row * 256;
    float v[4];
    float mx = -1e30f;
#pragma unroll
    for (int i = 0; i < 4; ++i) { v[i] = p[lane + i * 64]; mx = fmaxf(mx, v[i]); }
#pragma unroll
    for (int off = 32; off > 0; off >>= 1) mx = fmaxf(mx, __shfl_xor(mx, off));
    float sum = 0.f;
#pragma unroll
    for (int i = 0; i < 4; ++i) { v[i] = __expf(v[i] - mx); sum += v[i]; }
#pragma unroll
    for (int off = 32; off > 0; off >>= 1) sum += __shfl_xor(sum, off);
    float inv = 1.f / sum;
#pragma unroll
    for (int i = 0; i < 4; ++i) p[lane + i * 64] = v[i] * inv;
}

// ---------------- GRU recurrence: 1 wave, no LDS, no barriers ---------------
// __launch_bounds__(64,1): 1 wave/EU floor -> up to 512 VGPRs; 192-float
// weight array MUST stay in registers (VGPR_Count ~140 => spilled => rewrite).
__global__ __launch_bounds__(64, 1) void gru_rec_k(const float* __restrict__ xg,
                                                   const float* __restrict__ Wh,
                                                   const float* __restrict__ bh,
                                                   float* __restrict__ xout)
{
    int b = blockIdx.x, z = blockIdx.y;
    int m = z >> 1, d = z & 1;
    int n = threadIdx.x;
    const float* Whz = Wh + (long long)z * 12288;
    float wr[64], wz[64], wn[64];
#pragma unroll
    for (int k = 0; k < 64; ++k) {
        wr[k] = Whz[k * 192 + n];
        wz[k] = Whz[k * 192 + 64 + n];
        wn[k] = Whz[k * 192 + 128 + n];
    }
    float br = bh[z * 192 + n], bz = bh[z * 192 + 64 + n], bn = bh[z * 192 + 128 + n];
    const float* xgb = xg + (long long)z * 3145728 + (long long)b * 49152;
    float* xob = xout + (long long)m * 2097152 + (long long)b * 32768 + d * 64;

    float h = 0.f;
    int tt0 = d ? 255 : 0;
    float x0 = xgb[tt0 * 192 + n], x1 = xgb[tt0 * 192 + 64 + n], x2 = xgb[tt0 * 192 + 128 + n];
#pragma unroll 1
    for (int t = 0; t < 256; ++t) {
        int tt = d ? 255 - t : t;
        float nx0 = 0.f, nx1 = 0.f, nx2 = 0.f;
        if (t < 255) {
            const float* xr = xgb + (d ? tt - 1 : tt + 1) * 192;
            nx0 = xr[n]; nx1 = xr[64 + n]; nx2 = xr[128 + n];
        }
        float sr0 = br, sr1 = 0.f, sz0 = bz, sz1 = 0.f, sn0 = bn, sn1 = 0.f;
#pragma unroll
        for (int k = 0; k < 64; k += 2) {
            float h0 = rl(h, k), h1 = rl(h, k + 1);
            sr0 = fmaf(h0, wr[k], sr0); sz0 = fmaf(h0, wz[k], sz0); sn0 = fmaf(h0, wn[k], sn0);
            sr1 = fmaf(h1, wr[k + 1], sr1); sz1 = fmaf(h1, wz[k + 1], sz1); sn1 = fmaf(h1, wn[k + 1], sn1);
        }
        float r  = sigf(x0 + sr0 + sr1);
        float zz = sigf(x1 + sz0 + sz1);
        float nn = tanhf(x2 + r * (sn0 + sn1));   // r multiplies ONLY the h-dot
        h = (1.f - zz) * nn + zz * h;
        xob[tt * 128 + n] = h;
        x0 = nx0; x1 = nx1; x2 = nx2;
    }
}

// ---------------- LSTM recurrence: 256 threads, 2 cols/thread ----------------
// __launch_bounds__(256,1): allow ~300 VGPRs so w0[128]+w1[128] stay in regs.
__global__ __launch_bounds__(256, 1) void lstm_rec_k(const float* __restrict__ xg,
                                                     const float* __restrict__ Wh,
                                                     const float* __restrict__ bh,
                                                     float* __restrict__ sf)
{
    int b = blockIdx.x, d = blockIdx.y;
    int n = threadIdx.x, lane = n & 63;
    int c0 = n, c1 = n + 256;
    const float* Whz = Wh + (long long)d * 65536;
    float w0[128], w1[128];
#pragma unroll
    for (int k = 0; k < 128; ++k) { w0[k] = Whz[k * 512 + c0]; w1[k] = Whz[k * 512 + c1]; }
    float b0 = bh[d * 512 + c0], b1 = bh[d * 512 + c1];

    __shared__ float hs[2][128];
    __shared__ float g[512];
    float c = 0.f;
    if (n < 128) hs[0][n] = 0.f;
    __syncthreads();

    const float* xgb = xg + (long long)d * 8388608 + (long long)b * 131072;
    float* sfb = sf + (long long)b * 65536 + d * 128;

    int tt0 = d ? 255 : 0;
    float x0 = xgb[tt0 * 512 + c0], x1 = xgb[tt0 * 512 + c1];
#pragma unroll 1
    for (int t = 0; t < 256; ++t) {
        int p = t & 1;
        int tt = d ? 255 - t : t;
        float nx0 = 0.f, nx1 = 0.f;
        if (t < 255) {
            const float* xr = xgb + (d ? tt - 1 : tt + 1) * 512;
            nx0 = xr[c0]; nx1 = xr[c1];
        }
        float hA = hs[p][lane], hB = hs[p][64 + lane];
        float s0a = b0 + x0, s0b = 0.f, s1a = b1 + x1, s1b = 0.f;
#pragma unroll
        for (int k = 0; k < 64; k += 2) {
            float h0 = rl(hA, k), h1 = rl(hA, k + 1);
            s0a = fmaf(h0, w0[k], s0a);     s1a = fmaf(h0, w1[k], s1a);
            s0b = fmaf(h1, w0[k + 1], s0b); s1b = fmaf(h1, w1[k + 1], s1b);
        }
#pragma unroll
        for (int k = 0; k < 64; k += 2) {
            float h0 = rl(hB, k), h1 = rl(hB, k + 1);
            s0a = fmaf(h0, w0[64 + k], s0a);     s1a = fmaf(h0, w1[64 + k], s1a);
            s0b = fmaf(h1, w0[64 + k + 1], s0b); s1b = fmaf(h1, w1[64 + k + 1], s1b);
        }
        g[c0] = s0a + s0b;
        g[c1] = s1a + s1b;
        __syncthreads();
        if (n < 128) {
            float iv = g[n], fv = g[128 + n], gv = g[256 + n], ov = g[384 + n];
            c = sigf(fv) * c + sigf(iv) * tanhf(gv);
            float h2 = sigf(ov) * tanhf(c);
            hs[1 - p][n] = h2;
            sfb[tt * 256 + n] = h2;
        }
        __syncthreads();
        x0 = nx0; x1 = nx1;
    }
}

// ---------------- RGN recurrence: 192 threads, 2 cols/thread -----------------
// __launch_bounds__(192,1): keep 256-float weight arrays in registers.
__global__ __launch_bounds__(192, 1) void rgn_rec_k(const float* __restrict__ xg,
                                                    const float* __restrict__ Wh,
                                                    const float* __restrict__ state0,
                                                    const float* __restrict__ state1,
                                                    float* __restrict__ outbase)
{
    int b = blockIdx.x, d = blockIdx.y;
    int n = threadIdx.x, lane = n & 63;
    int c0 = n, c1 = n + 192;
    const float* Whz = Wh + (long long)d * 49152;
    float w0[128], w1[128];
#pragma unroll
    for (int k = 0; k < 128; ++k) { w0[k] = Whz[k * 384 + c0]; w1[k] = Whz[k * 384 + c1]; }

    __shared__ float hs[2][128];
    __shared__ float g[384];
    __shared__ float xs[128];
    const float* st = d ? state1 : state0;
    if (n < 128) hs[0][n] = st[b * 128 + n];
    __syncthreads();

    const float* xgb = xg + (long long)d * 6291456 + (long long)b * 98304;

    int tt0 = d ? 255 : 0;
    float x0 = xgb[tt0 * 384 + c0], x1 = xgb[tt0 * 384 + c1];
#pragma unroll 1
    for (int t = 0; t < 256; ++t) {
        int p = t & 1;
        int tt = d ? 255 - t : t;
        float nx0 = 0.f, nx1 = 0.f;
        if (t < 255) {
            const float* xr = xgb + (d ? tt - 1 : tt + 1) * 384;
            nx0 = xr[c0]; nx1 = xr[c1];
        }
        float hA = hs[p][lane], hB = hs[p][64 + lane];
        float s0a = 0.f, s0b = 0.f, s1a = 0.f, s1b = 0.f;
#pragma unroll
        for (int k = 0; k < 64; k += 2) {
            float h0 = rl(hA, k), h1 = rl(hA, k + 1);
            s0a = fmaf(h0, w0[k], s0a);     s1a = fmaf(h0, w1[k], s1a);
            s0b = fmaf(h1, w0[k + 1], s0b); s1b = fmaf(h1, w1[k + 1], s1b);
        }
#pragma unroll
        for (int k = 0; k < 64; k += 2) {
            float h0 = rl(hB, k), h1 = rl(hB, k + 1);
            s0a = fmaf(h0, w0[64 + k], s0a);     s1a = fmaf(h0, w1[64 + k], s1a);
            s0b = fmaf(h1, w0[64 + k + 1], s0b); s1b = fmaf(h1, w1[64 + k + 1], s1b);
        }
        // r,z gates (cols <256): x folds into g. n-gate (cols >=256): keep x
        // separate (r multiplies only the h-dot) -> stash x in xs[].
        g[c0] = s0a + s0b + x0;
        if (n >= 64) {                     // c1 >= 256: n-gate column (wave-uniform)
            g[c1] = s1a + s1b;
            xs[c1 - 256] = x1;
        } else {
            g[c1] = s1a + s1b + x1;
        }
        __syncthreads();
        if (n < 128) {
            float hold = (n < 64) ? hA : hB;   // == h_old[n]
            float r  = sigf(g[n]);
            float zz = sigf(g[128 + n]);
            float nn = tanhf(xs[n] + r * g[256 + n]);
            hs[1 - p][n] = (1.f - zz) * nn + zz * hold;
        }
        __syncthreads();
        x0 = nx0; x1 = nx1;
    }
    if (n < 128) outbase[(long long)d * 8192 + b * 128 + n] = hs[0][n];
}

// ---------------- final FC ----------------
__global__ __launch_bounds__(256) void fc_k(const float* __restrict__ o01,
                                            const float* __restrict__ f1W,
                                            const float* __restrict__ f1b,
                                            const float* __restrict__ f2W,
                                            const float* __restrict__ f2b,
                                            float* __restrict__ out)
{
    __shared__ float s[8192];
    __shared__ float h1[2048];
    int tid = threadIdx.x;
    for (int e = tid; e < 8192; e += 256) s[e] = o01[e] + o01[8192 + e];
    __syncthreads();
    for (int o = tid; o < 2048; o += 256) {
        int b = o >> 5, q = o & 31;
        float acc = f1b[q];
        for (int k = 0; k < 128; ++k) acc += s[b * 128 + k] * f1W[k * 32 + q];
        h1[o] = acc >= 0.f ? acc : 0.01f * acc;
    }
    __syncthreads();
    if (tid < 64) {
        float acc = f2b[0];
        for (int q = 0; q < 32; ++q) acc += h1[tid * 32 + q] * f2W[q];
        out[tid] = acc;
    }
}

// ============================ launch =========================================
extern "C" void kernel_launch(void* const* d_in, const int* in_sizes, int n_in,
                              void* d_out, int out_size, void* d_ws, size_t ws_size,
                              hipStream_t stream)
{
    const int*   sent     = (const int*)  d_in[0];
    const float* acoustic = (const float*)d_in[1];
    const float* video    = (const float*)d_in[2];
    const float* state0   = (const float*)d_in[3];
    const float* state1   = (const float*)d_in[4];
    const float* emb      = (const float*)d_in[5];
    const float* plW = (const float*)d_in[6],  *plb = (const float*)d_in[7];
    const float* paW = (const float*)d_in[8],  *pab = (const float*)d_in[9];
    const float* pvW = (const float*)d_in[10], *pvb = (const float*)d_in[11];
    const float* gWi = (const float*)d_in[12], *gWh = (const float*)d_in[13];
    const float* gbi = (const float*)d_in[14], *gbh = (const float*)d_in[15];
    const float* lWi = (const float*)d_in[16], *lWh = (const float*)d_in[17];
    const float* lbi = (const float*)d_in[18], *lbh = (const float*)d_in[19];
    const float* rWx = (const float*)d_in[20], *rWh = (const float*)d_in[21];
    const float* rb  = (const float*)d_in[22];
    const float* f1W = (const float*)d_in[23], *f1b = (const float*)d_in[24];
    const float* f2W = (const float*)d_in[25], *f2b = (const float*)d_in[26];
    float* ws  = (float*)d_ws;
    float* out = (float*)d_out;

    dim3 blk(64);

    // modality projections -> seq[3][16384][128]
    gemm_k<<<dim3(2, 256, 1), blk, 0, stream>>>(emb, 0, 1, 300, sent,
        plW, 0, 128, 0, plb, 0, ws + WS_SEQ, 0, 128, 300, 1.f, 0);
    gemm_k<<<dim3(2, 256, 1), blk, 0, stream>>>(acoustic, 0, 1, 74, nullptr,
        paW, 0, 128, 0, pab, 0, ws + WS_SEQ + 2097152, 0, 128, 74, 1.f, 0);
    gemm_k<<<dim3(2, 256, 1), blk, 0, stream>>>(video, 0, 1, 35, nullptr,
        pvW, 0, 128, 0, pvb, 0, ws + WS_SEQ + 4194304, 0, 128, 35, 1.f, 0);

    // GRU input projections, z = modality*2 + dir
    gemm_k<<<dim3(3, 256, 6), blk, 0, stream>>>(ws + WS_SEQ, 2097152, 2, 128, nullptr,
        gWi, 24576, 192, 0, gbi, 192, ws + WS_XGGRU, 3145728, 192, 128, 1.f, 0);

    // GRU recurrences -> x[3][16384][128]
    gru_rec_k<<<dim3(64, 6), dim3(64), 0, stream>>>(ws + WS_XGGRU, gWh, gbh, ws + WS_X);

    // tstep = concat(x_l, x_a, x_v)
    copy_tstep_k<<<dim3(24576), dim3(256), 0, stream>>>(ws + WS_X, ws + WS_TSTEP);

    // attention: two race-free rounds of 3 pairs (distinct q-modality per round)
    att_score_k<<<dim3(4, 4, 192), blk, 0, stream>>>(ws + WS_X, ws + WS_S,
        0, 1, 2, 1, 0, 0);
    softmax_k<<<dim3(12288), dim3(256), 0, stream>>>(ws + WS_S);
    att_apply_k<<<dim3(2, 4, 192), blk, 0, stream>>>(ws + WS_S, ws + WS_X,
        ws + WS_TSTEP, 0, 1, 2, 1, 0, 0);
    att_score_k<<<dim3(4, 4, 192), blk, 0, stream>>>(ws + WS_X, ws + WS_S,
        0, 1, 2, 2, 2, 1);
    softmax_k<<<dim3(12288), dim3(256), 0, stream>>>(ws + WS_S);
    att_apply_k<<<dim3(2, 4, 192), blk, 0, stream>>>(ws + WS_S, ws + WS_X,
        ws + WS_TSTEP, 0, 1, 2, 2, 2, 1);

    // LSTM input projections
    gemm_k<<<dim3(8, 256, 2), blk, 0, stream>>>(ws + WS_TSTEP, 0, 1, 384, nullptr,
        lWi, 196608, 512, 0, lbi, 512, ws + WS_XGLSTM, 8388608, 512, 384, 1.f, 0);

    // BiLSTM recurrences -> step_fusion[16384][256]
    lstm_rec_k<<<dim3(64, 2), dim3(256), 0, stream>>>(ws + WS_XGLSTM, lWh, lbh, ws + WS_SF);

    // RGN input projections
    gemm_k<<<dim3(6, 256, 2), blk, 0, stream>>>(ws + WS_SF, 0, 1, 256, nullptr,
        rWx, 98304, 384, 0, rb, 384, ws + WS_XGRGN, 6291456, 384, 256, 1.f, 0);

    // RGN recurrences -> out0/out1 [64][128]
    rgn_rec_k<<<dim3(64, 2), dim3(192), 0, stream>>>(ws + WS_XGRGN, rWh, state0, state1,
                                                     ws + WS_OUT0);

    // final FC -> d_out [64]
    fc_k<<<dim3(1), dim3(256), 0, stream>>>(ws + WS_OUT0, f1W, f1b, f2W, f2b, out);
}

// Round 6
// 2004.499 us; speedup vs baseline: 1.0108x; 1.0108x over previous
//
#include <hip/hip_runtime.h>

// ---------------- workspace layout (float offsets) ----------------
#define WS_SEQ      0LL          // [3][16384][128]
#define WS_XGGRU    6291456LL    // [6][16384][192]
#define WS_X        0LL          // [3][16384][128]
#define WS_TSTEP    18874368LL   // [16384][384]
#define WS_S        6291456LL    // [192][65536] scores (3 pairs x 64 batch)
#define WS_XGLSTM   0LL          // [2][16384][512]
#define WS_SF       16777216LL   // [16384][256]
#define WS_XGRGN    0LL          // [2][16384][384]
#define WS_OUT0     20971520LL   // [2][64][128]

__device__ __forceinline__ float sigf(float x) { return 1.f / (1.f + __expf(-x)); }
// readlane: lane index MUST be compile-time uniform (unrolled loops only)
__device__ __forceinline__ float rl(float v, int i) {
    return __int_as_float(__builtin_amdgcn_readlane(__float_as_int(v), i));
}

// 16-float register vector: a single SSA value (16 VGPRs) -> cannot be
// demoted to scratch the way float arrays are (promote-alloca limit ~16).
typedef float vf16 __attribute__((ext_vector_type(16)));

// load 16 strided floats into a vf16 (coalesced across lanes)
#define LD16(V, P, S) { _Pragma("unroll") \
    for (int _j = 0; _j < 16; ++_j) (V)[_j] = (P)[_j * (S)]; }
// ACC += sum_j h[B+j] * V[j]  (readlane broadcast; CSE merges duplicate rl's)
#define DOT16(ACC, V, H, B) { _Pragma("unroll") \
    for (int _j = 0; _j < 16; ++_j) (ACC) = fmaf(rl((H), (B) + _j), (V)[_j], (ACC)); }

// ---------------- shared fp32 GEMM body: 64x64 tile, 1 wave, 8x8 micro -------
__device__ __forceinline__ void gemm_body(
    const float* __restrict__ Ab, int lda, const int* __restrict__ idx,
    const float* __restrict__ Wb, int wld, int wtrans,
    const float* __restrict__ bb,
    float* __restrict__ Cb, int ldc,
    int K, float alpha, int accum)
{
    int m0 = blockIdx.y * 64, n0 = blockIdx.x * 64;
    int t = threadIdx.x;
    int tx = t & 7, ty = t >> 3;

    __shared__ __align__(16) float As[16][68];
    __shared__ __align__(16) float Ws[16][68];

    float acc[8][8];
#pragma unroll
    for (int i = 0; i < 8; ++i)
#pragma unroll
        for (int j = 0; j < 8; ++j) acc[i][j] = 0.f;

    long long arow[4];
#pragma unroll
    for (int i = 0; i < 4; ++i) {
        int m = (t + i * 64) >> 2;
        arow[i] = idx ? (long long)idx[m0 + m] : (long long)(m0 + m);
    }
    const bool a_vec = ((lda & 3) == 0);

    for (int k0 = 0; k0 < K; k0 += 16) {
#pragma unroll
        for (int i = 0; i < 4; ++i) {
            int j = t + i * 64;
            int m = j >> 2, kq = j & 3;
            int kk = k0 + kq * 4;
            const float* p = Ab + arow[i] * (long long)lda + kk;
            float4 v = {0.f, 0.f, 0.f, 0.f};
            if (a_vec && kk + 3 < K) {
                v = *(const float4*)p;
            } else {
                if (kk + 0 < K) v.x = p[0];
                if (kk + 1 < K) v.y = p[1];
                if (kk + 2 < K) v.z = p[2];
                if (kk + 3 < K) v.w = p[3];
            }
            As[kq * 4 + 0][m] = v.x; As[kq * 4 + 1][m] = v.y;
            As[kq * 4 + 2][m] = v.z; As[kq * 4 + 3][m] = v.w;
        }
        if (!wtrans) {
#pragma unroll
            for (int i = 0; i < 4; ++i) {
                int j = t + i * 64;
                int k = j >> 4, nq = j & 15;
                float4 v = {0.f, 0.f, 0.f, 0.f};
                if (k0 + k < K)
                    v = *(const float4*)(Wb + (long long)(k0 + k) * wld + n0 + nq * 4);
                *(float4*)&Ws[k][nq * 4] = v;
            }
        } else {
#pragma unroll
            for (int i = 0; i < 4; ++i) {
                int j = t + i * 64;
                int n = j >> 2, kq = j & 3;
                int kk = k0 + kq * 4;
                const float* p = Wb + (long long)(n0 + n) * wld + kk;
                float4 v = {0.f, 0.f, 0.f, 0.f};
                if (kk + 3 < K) v = *(const float4*)p;
                else {
                    if (kk + 0 < K) v.x = p[0];
                    if (kk + 1 < K) v.y = p[1];
                    if (kk + 2 < K) v.z = p[2];
                    if (kk + 3 < K) v.w = p[3];
                }
                Ws[kq * 4 + 0][n] = v.x; Ws[kq * 4 + 1][n] = v.y;
                Ws[kq * 4 + 2][n] = v.z; Ws[kq * 4 + 3][n] = v.w;
            }
        }
        __syncthreads();
#pragma unroll
        for (int k = 0; k < 16; ++k) {
            float4 a0 = *(const float4*)&As[k][ty * 8];
            float4 a1 = *(const float4*)&As[k][ty * 8 + 4];
            float4 b0 = *(const float4*)&Ws[k][tx * 8];
            float4 b1 = *(const float4*)&Ws[k][tx * 8 + 4];
            float av[8] = {a0.x, a0.y, a0.z, a0.w, a1.x, a1.y, a1.z, a1.w};
            float bv[8] = {b0.x, b0.y, b0.z, b0.w, b1.x, b1.y, b1.z, b1.w};
#pragma unroll
            for (int i = 0; i < 8; ++i)
#pragma unroll
                for (int j = 0; j < 8; ++j)
                    acc[i][j] = fmaf(av[i], bv[j], acc[i][j]);
        }
        __syncthreads();
    }

#pragma unroll
    for (int i = 0; i < 8; ++i) {
        long long gm = m0 + ty * 8 + i;
#pragma unroll
        for (int jq = 0; jq < 2; ++jq) {
            float* cp = Cb + gm * ldc + n0 + tx * 8 + jq * 4;
            float4 v;
            v.x = alpha * acc[i][jq * 4 + 0]; v.y = alpha * acc[i][jq * 4 + 1];
            v.z = alpha * acc[i][jq * 4 + 2]; v.w = alpha * acc[i][jq * 4 + 3];
            if (bb) {
                const float* bp = bb + n0 + tx * 8 + jq * 4;
                v.x += bp[0]; v.y += bp[1]; v.z += bp[2]; v.w += bp[3];
            }
            if (accum) {
                float4 o = *(const float4*)cp;
                v.x += o.x; v.y += o.y; v.z += o.z; v.w += o.w;
            }
            *(float4*)cp = v;
        }
    }
}

// ---------------- generic GEMM launcher-kernel ----------------
__global__ __launch_bounds__(64) void gemm_k(
    const float* __restrict__ A, long long a_z, int a_zdiv, int lda,
    const int* __restrict__ idx,
    const float* __restrict__ W, long long w_z, int wld, int wtrans,
    const float* __restrict__ bias, int bias_z,
    float* __restrict__ C, long long c_z, int ldc,
    int K, float alpha, int accum)
{
    int z = blockIdx.z;
    gemm_body(A + (long long)(z / a_zdiv) * a_z, lda, idx,
              W + (long long)z * w_z, wld, wtrans,
              bias ? bias + (long long)z * bias_z : nullptr,
              C + (long long)z * c_z, ldc, K, alpha, accum);
}

// ---------------- batched attention score: S[z] = scale * q_b @ kv_b^T ------
__global__ __launch_bounds__(64) void att_score_k(
    const float* __restrict__ X, float* __restrict__ S,
    int q0, int q1, int q2, int k0, int k1, int k2)
{
    int z = blockIdx.z;
    int pair = z >> 6, b = z & 63;
    int qi = pair == 0 ? q0 : (pair == 1 ? q1 : q2);
    int ki = pair == 0 ? k0 : (pair == 1 ? k1 : k2);
    gemm_body(X + (long long)qi * 2097152 + (long long)b * 32768, 128, nullptr,
              X + (long long)ki * 2097152 + (long long)b * 32768, 128, 1,
              nullptr,
              S + (long long)z * 65536, 256, 128, 0.08838834764831845f, 0);
}

// ---------------- batched attention apply: tstep_slice += P_b @ kv_b --------
__global__ __launch_bounds__(64) void att_apply_k(
    const float* __restrict__ S, const float* __restrict__ X,
    float* __restrict__ tstep,
    int q0, int q1, int q2, int k0, int k1, int k2)
{
    int z = blockIdx.z;
    int pair = z >> 6, b = z & 63;
    int qi = pair == 0 ? q0 : (pair == 1 ? q1 : q2);
    int ki = pair == 0 ? k0 : (pair == 1 ? k1 : k2);
    gemm_body(S + (long long)z * 65536, 256, nullptr,
              X + (long long)ki * 2097152 + (long long)b * 32768, 128, 0,
              nullptr,
              tstep + (long long)qi * 128 + (long long)b * 98304, 384,
              256, 1.f, 1);
}

// ---------------- tstep init ----------------
__global__ __launch_bounds__(256) void copy_tstep_k(const float* __restrict__ x,
                                                    float* __restrict__ tstep)
{
    int o = blockIdx.x * 256 + threadIdx.x;
    int c = o % 384;
    int row = o / 384;
    int m = c >> 7, cc = c & 127;
    tstep[o] = x[(long long)m * 2097152 + (long long)row * 128 + cc];
}

// ---------------- softmax over rows of 256 (one wave per row) ----------------
__global__ __launch_bounds__(256) void softmax_k(float* __restrict__ S)
{
    int wave = threadIdx.x >> 6, lane = threadIdx.x & 63;
    int row = blockIdx.x * 4 + wave;
    float* p = S + (long long)row * 256;
    float v[4];
    float mx = -1e30f;
#pragma unroll
    for (int i = 0; i < 4; ++i) { v[i] = p[lane + i * 64]; mx = fmaxf(mx, v[i]); }
#pragma unroll
    for (int off = 32; off > 0; off >>= 1) mx = fmaxf(mx, __shfl_xor(mx, off));
    float sum = 0.f;
#pragma unroll
    for (int i = 0; i < 4; ++i) { v[i] = __expf(v[i] - mx); sum += v[i]; }
#pragma unroll
    for (int off = 32; off > 0; off >>= 1) sum += __shfl_xor(sum, off);
    float inv = 1.f / sum;
#pragma unroll
    for (int i = 0; i < 4; ++i) p[lane + i * 64] = v[i] * inv;
}

// ---------------- GRU recurrence: 1 wave, weights in vf16 registers ----------
__global__ __launch_bounds__(64) __attribute__((amdgpu_waves_per_eu(1, 1)))
void gru_rec_k(const float* __restrict__ xg,
               const float* __restrict__ Wh,
               const float* __restrict__ bh,
               float* __restrict__ xout)
{
    int b = blockIdx.x, z = blockIdx.y;
    int m = z >> 1, d = z & 1;
    int n = threadIdx.x;
    const float* Whz = Wh + (long long)z * 12288;
    // wr[k]=Whz[k*192+n], wz=+64, wn=+128; k in [0,64)
    vf16 R0, R1, R2, R3, Z0, Z1, Z2, Z3, N0, N1, N2, N3;
    LD16(R0, Whz + 0 * 3072 + n, 192);       LD16(R1, Whz + 1 * 3072 + n, 192);
    LD16(R2, Whz + 2 * 3072 + n, 192);       LD16(R3, Whz + 3 * 3072 + n, 192);
    LD16(Z0, Whz + 0 * 3072 + 64 + n, 192);  LD16(Z1, Whz + 1 * 3072 + 64 + n, 192);
    LD16(Z2, Whz + 2 * 3072 + 64 + n, 192);  LD16(Z3, Whz + 3 * 3072 + 64 + n, 192);
    LD16(N0, Whz + 0 * 3072 + 128 + n, 192); LD16(N1, Whz + 1 * 3072 + 128 + n, 192);
    LD16(N2, Whz + 2 * 3072 + 128 + n, 192); LD16(N3, Whz + 3 * 3072 + 128 + n, 192);
    float br = bh[z * 192 + n], bz = bh[z * 192 + 64 + n], bn = bh[z * 192 + 128 + n];
    const float* xgb = xg + (long long)z * 3145728 + (long long)b * 49152;
    float* xob = xout + (long long)m * 2097152 + (long long)b * 32768 + d * 64;

    float h = 0.f;
    int tt0 = d ? 255 : 0;
    float x0 = xgb[tt0 * 192 + n], x1 = xgb[tt0 * 192 + 64 + n], x2 = xgb[tt0 * 192 + 128 + n];
#pragma unroll 1
    for (int t = 0; t < 256; ++t) {
        int tt = d ? 255 - t : t;
        float nx0 = 0.f, nx1 = 0.f, nx2 = 0.f;
        if (t < 255) {
            const float* xr = xgb + (d ? tt - 1 : tt + 1) * 192;
            nx0 = xr[n]; nx1 = xr[64 + n]; nx2 = xr[128 + n];
        }
        float sr0 = br, sr1 = 0.f, sz0 = bz, sz1 = 0.f, sn0 = bn, sn1 = 0.f;
        DOT16(sr0, R0, h, 0);  DOT16(sr1, R1, h, 16);
        DOT16(sr0, R2, h, 32); DOT16(sr1, R3, h, 48);
        DOT16(sz0, Z0, h, 0);  DOT16(sz1, Z1, h, 16);
        DOT16(sz0, Z2, h, 32); DOT16(sz1, Z3, h, 48);
        DOT16(sn0, N0, h, 0);  DOT16(sn1, N1, h, 16);
        DOT16(sn0, N2, h, 32); DOT16(sn1, N3, h, 48);
        float r  = sigf(x0 + sr0 + sr1);
        float zz = sigf(x1 + sz0 + sz1);
        float nn = tanhf(x2 + r * (sn0 + sn1));   // r multiplies ONLY the h-dot
        h = (1.f - zz) * nn + zz * h;
        xob[tt * 128 + n] = h;
        x0 = nx0; x1 = nx1; x2 = nx2;
    }
}

// ---------------- LSTM recurrence: 256 thr, 2 cols/thread, vf16 weights ------
__global__ __launch_bounds__(256) __attribute__((amdgpu_waves_per_eu(1, 1)))
void lstm_rec_k(const float* __restrict__ xg,
                const float* __restrict__ Wh,
                const float* __restrict__ bh,
                float* __restrict__ sf)
{
    int b = blockIdx.x, d = blockIdx.y;
    int n = threadIdx.x, lane = n & 63;
    int c0 = n, c1 = n + 256;
    const float* Whz = Wh + (long long)d * 65536;
    // col c weights: w[k] = Whz[k*512 + c]; Aq covers k = q*16 .. q*16+15
    vf16 A0, A1, A2, A3, A4, A5, A6, A7, B0, B1, B2, B3, B4, B5, B6, B7;
    LD16(A0, Whz + 0 * 8192 + c0, 512); LD16(A1, Whz + 1 * 8192 + c0, 512);
    LD16(A2, Whz + 2 * 8192 + c0, 512); LD16(A3, Whz + 3 * 8192 + c0, 512);
    LD16(A4, Whz + 4 * 8192 + c0, 512); LD16(A5, Whz + 5 * 8192 + c0, 512);
    LD16(A6, Whz + 6 * 8192 + c0, 512); LD16(A7, Whz + 7 * 8192 + c0, 512);
    LD16(B0, Whz + 0 * 8192 + c1, 512); LD16(B1, Whz + 1 * 8192 + c1, 512);
    LD16(B2, Whz + 2 * 8192 + c1, 512); LD16(B3, Whz + 3 * 8192 + c1, 512);
    LD16(B4, Whz + 4 * 8192 + c1, 512); LD16(B5, Whz + 5 * 8192 + c1, 512);
    LD16(B6, Whz + 6 * 8192 + c1, 512); LD16(B7, Whz + 7 * 8192 + c1, 512);
    float b0 = bh[d * 512 + c0], b1 = bh[d * 512 + c1];

    __shared__ float hs[2][128];
    __shared__ float g[512];
    float c = 0.f;
    if (n < 128) hs[0][n] = 0.f;
    __syncthreads();

    const float* xgb = xg + (long long)d * 8388608 + (long long)b * 131072;
    float* sfb = sf + (long long)b * 65536 + d * 128;

    int tt0 = d ? 255 : 0;
    float x0 = xgb[tt0 * 512 + c0], x1 = xgb[tt0 * 512 + c1];
#pragma unroll 1
    for (int t = 0; t < 256; ++t) {
        int p = t & 1;
        int tt = d ? 255 - t : t;
        float nx0 = 0.f, nx1 = 0.f;
        if (t < 255) {
            const float* xr = xgb + (d ? tt - 1 : tt + 1) * 512;
            nx0 = xr[c0]; nx1 = xr[c1];
        }
        float hA = hs[p][lane], hB = hs[p][64 + lane];
        float s0a = b0 + x0, s0b = 0.f, s0c = 0.f, s0d = 0.f;
        float s1a = b1 + x1, s1b = 0.f, s1c = 0.f, s1d = 0.f;
        DOT16(s0a, A0, hA, 0);  DOT16(s0b, A1, hA, 16);
        DOT16(s0c, A2, hA, 32); DOT16(s0d, A3, hA, 48);
        DOT16(s1a, B0, hA, 0);  DOT16(s1b, B1, hA, 16);
        DOT16(s1c, B2, hA, 32); DOT16(s1d, B3, hA, 48);
        DOT16(s0a, A4, hB, 0);  DOT16(s0b, A5, hB, 16);
        DOT16(s0c, A6, hB, 32); DOT16(s0d, A7, hB, 48);
        DOT16(s1a, B4, hB, 0);  DOT16(s1b, B5, hB, 16);
        DOT16(s1c, B6, hB, 32); DOT16(s1d, B7, hB, 48);
        g[c0] = (s0a + s0b) + (s0c + s0d);
        g[c1] = (s1a + s1b) + (s1c + s1d);
        __syncthreads();
        if (n < 128) {
            float iv = g[n], fv = g[128 + n], gv = g[256 + n], ov = g[384 + n];
            c = sigf(fv) * c + sigf(iv) * tanhf(gv);
            float h2 = sigf(ov) * tanhf(c);
            hs[1 - p][n] = h2;
            sfb[tt * 256 + n] = h2;
        }
        __syncthreads();
        x0 = nx0; x1 = nx1;
    }
}

// ---------------- RGN recurrence: 192 thr, 2 cols/thread, vf16 weights -------
__global__ __launch_bounds__(192) __attribute__((amdgpu_waves_per_eu(1, 1)))
void rgn_rec_k(const float* __restrict__ xg,
               const float* __restrict__ Wh,
               const float* __restrict__ state0,
               const float* __restrict__ state1,
               float* __restrict__ outbase)
{
    int b = blockIdx.x, d = blockIdx.y;
    int n = threadIdx.x, lane = n & 63;
    int c0 = n, c1 = n + 192;
    const float* Whz = Wh + (long long)d * 49152;
    vf16 A0, A1, A2, A3, A4, A5, A6, A7, B0, B1, B2, B3, B4, B5, B6, B7;
    LD16(A0, Whz + 0 * 6144 + c0, 384); LD16(A1, Whz + 1 * 6144 + c0, 384);
    LD16(A2, Whz + 2 * 6144 + c0, 384); LD16(A3, Whz + 3 * 6144 + c0, 384);
    LD16(A4, Whz + 4 * 6144 + c0, 384); LD16(A5, Whz + 5 * 6144 + c0, 384);
    LD16(A6, Whz + 6 * 6144 + c0, 384); LD16(A7, Whz + 7 * 6144 + c0, 384);
    LD16(B0, Whz + 0 * 6144 + c1, 384); LD16(B1, Whz + 1 * 6144 + c1, 384);
    LD16(B2, Whz + 2 * 6144 + c1, 384); LD16(B3, Whz + 3 * 6144 + c1, 384);
    LD16(B4, Whz + 4 * 6144 + c1, 384); LD16(B5, Whz + 5 * 6144 + c1, 384);
    LD16(B6, Whz + 6 * 6144 + c1, 384); LD16(B7, Whz + 7 * 6144 + c1, 384);

    __shared__ float hs[2][128];
    __shared__ float g[384];
    __shared__ float xs[128];
    const float* st = d ? state1 : state0;
    if (n < 128) hs[0][n] = st[b * 128 + n];
    __syncthreads();

    const float* xgb = xg + (long long)d * 6291456 + (long long)b * 98304;

    int tt0 = d ? 255 : 0;
    float x0 = xgb[tt0 * 384 + c0], x1 = xgb[tt0 * 384 + c1];
#pragma unroll 1
    for (int t = 0; t < 256; ++t) {
        int p = t & 1;
        int tt = d ? 255 - t : t;
        float nx0 = 0.f, nx1 = 0.f;
        if (t < 255) {
            const float* xr = xgb + (d ? tt - 1 : tt + 1) * 384;
            nx0 = xr[c0]; nx1 = xr[c1];
        }
        float hA = hs[p][lane], hB = hs[p][64 + lane];
        float s0a = 0.f, s0b = 0.f, s0c = 0.f, s0d = 0.f;
        float s1a = 0.f, s1b = 0.f, s1c = 0.f, s1d = 0.f;
        DOT16(s0a, A0, hA, 0);  DOT16(s0b, A1, hA, 16);
        DOT16(s0c, A2, hA, 32); DOT16(s0d, A3, hA, 48);
        DOT16(s1a, B0, hA, 0);  DOT16(s1b, B1, hA, 16);
        DOT16(s1c, B2, hA, 32); DOT16(s1d, B3, hA, 48);
        DOT16(s0a, A4, hB, 0);  DOT16(s0b, A5, hB, 16);
        DOT16(s0c, A6, hB, 32); DOT16(s0d, A7, hB, 48);
        DOT16(s1a, B4, hB, 0);  DOT16(s1b, B5, hB, 16);
        DOT16(s1c, B6, hB, 32); DOT16(s1d, B7, hB, 48);
        // r,z gate cols (<256): fold x into g. n-gate cols (>=256): keep x
        // separate (r multiplies only the h-dot) -> stash x in xs[].
        g[c0] = (s0a + s0b) + (s0c + s0d) + x0;
        if (n >= 64) {                     // c1 >= 256: n-gate column (wave-uniform)
            g[c1] = (s1a + s1b) + (s1c + s1d);
            xs[c1 - 256] = x1;
        } else {
            g[c1] = (s1a + s1b) + (s1c + s1d) + x1;
        }
        __syncthreads();
        if (n < 128) {
            float hold = (n < 64) ? hA : hB;   // == h_old[n]
            float r  = sigf(g[n]);
            float zz = sigf(g[128 + n]);
            float nn = tanhf(xs[n] + r * g[256 + n]);
            hs[1 - p][n] = (1.f - zz) * nn + zz * hold;
        }
        __syncthreads();
        x0 = nx0; x1 = nx1;
    }
    if (n < 128) outbase[(long long)d * 8192 + b * 128 + n] = hs[0][n];
}

// ---------------- final FC ----------------
__global__ __launch_bounds__(256) void fc_k(const float* __restrict__ o01,
                                            const float* __restrict__ f1W,
                                            const float* __restrict__ f1b,
                                            const float* __restrict__ f2W,
                                            const float* __restrict__ f2b,
                                            float* __restrict__ out)
{
    __shared__ float s[8192];
    __shared__ float h1[2048];
    int tid = threadIdx.x;
    for (int e = tid; e < 8192; e += 256) s[e] = o01[e] + o01[8192 + e];
    __syncthreads();
    for (int o = tid; o < 2048; o += 256) {
        int b = o >> 5, q = o & 31;
        float acc = f1b[q];
        for (int k = 0; k < 128; ++k) acc += s[b * 128 + k] * f1W[k * 32 + q];
        h1[o] = acc >= 0.f ? acc : 0.01f * acc;
    }
    __syncthreads();
    if (tid < 64) {
        float acc = f2b[0];
        for (int q = 0; q < 32; ++q) acc += h1[tid * 32 + q] * f2W[q];
        out[tid] = acc;
    }
}

// ============================ launch =========================================
extern "C" void kernel_launch(void* const* d_in, const int* in_sizes, int n_in,
                              void* d_out, int out_size, void* d_ws, size_t ws_size,
                              hipStream_t stream)
{
    const int*   sent     = (const int*)  d_in[0];
    const float* acoustic = (const float*)d_in[1];
    const float* video    = (const float*)d_in[2];
    const float* state0   = (const float*)d_in[3];
    const float* state1   = (const float*)d_in[4];
    const float* emb      = (const float*)d_in[5];
    const float* plW = (const float*)d_in[6],  *plb = (const float*)d_in[7];
    const float* paW = (const float*)d_in[8],  *pab = (const float*)d_in[9];
    const float* pvW = (const float*)d_in[10], *pvb = (const float*)d_in[11];
    const float* gWi = (const float*)d_in[12], *gWh = (const float*)d_in[13];
    const float* gbi = (const float*)d_in[14], *gbh = (const float*)d_in[15];
    const float* lWi = (const float*)d_in[16], *lWh = (const float*)d_in[17];
    const float* lbi = (const float*)d_in[18], *lbh = (const float*)d_in[19];
    const float* rWx = (const float*)d_in[20], *rWh = (const float*)d_in[21];
    const float* rb  = (const float*)d_in[22];
    const float* f1W = (const float*)d_in[23], *f1b = (const float*)d_in[24];
    const float* f2W = (const float*)d_in[25], *f2b = (const float*)d_in[26];
    float* ws  = (float*)d_ws;
    float* out = (float*)d_out;

    dim3 blk(64);

    // modality projections -> seq[3][16384][128]
    gemm_k<<<dim3(2, 256, 1), blk, 0, stream>>>(emb, 0, 1, 300, sent,
        plW, 0, 128, 0, plb, 0, ws + WS_SEQ, 0, 128, 300, 1.f, 0);
    gemm_k<<<dim3(2, 256, 1), blk, 0, stream>>>(acoustic, 0, 1, 74, nullptr,
        paW, 0, 128, 0, pab, 0, ws + WS_SEQ + 2097152, 0, 128, 74, 1.f, 0);
    gemm_k<<<dim3(2, 256, 1), blk, 0, stream>>>(video, 0, 1, 35, nullptr,
        pvW, 0, 128, 0, pvb, 0, ws + WS_SEQ + 4194304, 0, 128, 35, 1.f, 0);

    // GRU input projections, z = modality*2 + dir
    gemm_k<<<dim3(3, 256, 6), blk, 0, stream>>>(ws + WS_SEQ, 2097152, 2, 128, nullptr,
        gWi, 24576, 192, 0, gbi, 192, ws + WS_XGGRU, 3145728, 192, 128, 1.f, 0);

    // GRU recurrences -> x[3][16384][128]
    gru_rec_k<<<dim3(64, 6), dim3(64), 0, stream>>>(ws + WS_XGGRU, gWh, gbh, ws + WS_X);

    // tstep = concat(x_l, x_a, x_v)
    copy_tstep_k<<<dim3(24576), dim3(256), 0, stream>>>(ws + WS_X, ws + WS_TSTEP);

    // attention: two race-free rounds of 3 pairs (distinct q-modality per round)
    att_score_k<<<dim3(4, 4, 192), blk, 0, stream>>>(ws + WS_X, ws + WS_S,
        0, 1, 2, 1, 0, 0);
    softmax_k<<<dim3(12288), dim3(256), 0, stream>>>(ws + WS_S);
    att_apply_k<<<dim3(2, 4, 192), blk, 0, stream>>>(ws + WS_S, ws + WS_X,
        ws + WS_TSTEP, 0, 1, 2, 1, 0, 0);
    att_score_k<<<dim3(4, 4, 192), blk, 0, stream>>>(ws + WS_X, ws + WS_S,
        0, 1, 2, 2, 2, 1);
    softmax_k<<<dim3(12288), dim3(256), 0, stream>>>(ws + WS_S);
    att_apply_k<<<dim3(2, 4, 192), blk, 0, stream>>>(ws + WS_S, ws + WS_X,
        ws + WS_TSTEP, 0, 1, 2, 2, 2, 1);

    // LSTM input projections
    gemm_k<<<dim3(8, 256, 2), blk, 0, stream>>>(ws + WS_TSTEP, 0, 1, 384, nullptr,
        lWi, 196608, 512, 0, lbi, 512, ws + WS_XGLSTM, 8388608, 512, 384, 1.f, 0);

    // BiLSTM recurrences -> step_fusion[16384][256]
    lstm_rec_k<<<dim3(64, 2), dim3(256), 0, stream>>>(ws + WS_XGLSTM, lWh, lbh, ws + WS_SF);

    // RGN input projections
    gemm_k<<<dim3(6, 256, 2), blk, 0, stream>>>(ws + WS_SF, 0, 1, 256, nullptr,
        rWx, 98304, 384, 0, rb, 384, ws + WS_XGRGN, 6291456, 384, 256, 1.f, 0);

    // RGN recurrences -> out0/out1 [64][128]
    rgn_rec_k<<<dim3(64, 2), dim3(192), 0, stream>>>(ws + WS_XGRGN, rWh, state0, state1,
                                                     ws + WS_OUT0);

    // final FC -> d_out [64]
    fc_k<<<dim3(1), dim3(256), 0, stream>>>(ws + WS_OUT0, f1W, f1b, f2W, f2b, out);
}

// Round 7
// 1686.246 us; speedup vs baseline: 1.2016x; 1.1887x over previous
//
#include <hip/hip_runtime.h>

// ---------------- workspace layout (float offsets) ----------------
#define WS_SEQ      0LL          // [3][16384][128]
#define WS_XGGRU    6291456LL    // [6][16384][192]
#define WS_X        0LL          // [3][16384][128]
#define WS_TSTEP    18874368LL   // [16384][384]
#define WS_S        6291456LL    // [192][65536] scores (3 pairs x 64 batch)
#define WS_XGLSTM   0LL          // [2][16384][512]
#define WS_SF       16777216LL   // [16384][256]
#define WS_XGRGN    0LL          // [2][16384][384]
#define WS_OUT0     20971520LL   // [2][64][128]

__device__ __forceinline__ float sigf(float x) { return 1.f / (1.f + __expf(-x)); }
// readlane: lane index MUST be compile-time uniform (unrolled loops only)
__device__ __forceinline__ float rl(float v, int i) {
    return __int_as_float(__builtin_amdgcn_readlane(__float_as_int(v), i));
}

// 16-float register vector (single SSA value = 16 VGPRs, no alloca)
typedef float vf16 __attribute__((ext_vector_type(16)));

#define LD16(V, P, S) { _Pragma("unroll") \
    for (int _j = 0; _j < 16; ++_j) (V)[_j] = (P)[_j * (S)]; }
#define DOT16(ACC, V, H, B) { _Pragma("unroll") \
    for (int _j = 0; _j < 16; ++_j) (ACC) = fmaf(rl((H), (B) + _j), (V)[_j], (ACC)); }

// ---------------- shared fp32 GEMM body: 64x64 tile, 1 wave, 8x8 micro -------
__device__ __forceinline__ void gemm_body(
    const float* __restrict__ Ab, int lda, const int* __restrict__ idx,
    const float* __restrict__ Wb, int wld, int wtrans,
    const float* __restrict__ bb,
    float* __restrict__ Cb, int ldc,
    int K, float alpha, int accum)
{
    int m0 = blockIdx.y * 64, n0 = blockIdx.x * 64;
    int t = threadIdx.x;
    int tx = t & 7, ty = t >> 3;

    __shared__ __align__(16) float As[16][68];
    __shared__ __align__(16) float Ws[16][68];

    float acc[8][8];
#pragma unroll
    for (int i = 0; i < 8; ++i)
#pragma unroll
        for (int j = 0; j < 8; ++j) acc[i][j] = 0.f;

    long long arow[4];
#pragma unroll
    for (int i = 0; i < 4; ++i) {
        int m = (t + i * 64) >> 2;
        arow[i] = idx ? (long long)idx[m0 + m] : (long long)(m0 + m);
    }
    const bool a_vec = ((lda & 3) == 0);

    for (int k0 = 0; k0 < K; k0 += 16) {
#pragma unroll
        for (int i = 0; i < 4; ++i) {
            int j = t + i * 64;
            int m = j >> 2, kq = j & 3;
            int kk = k0 + kq * 4;
            const float* p = Ab + arow[i] * (long long)lda + kk;
            float4 v = {0.f, 0.f, 0.f, 0.f};
            if (a_vec && kk + 3 < K) {
                v = *(const float4*)p;
            } else {
                if (kk + 0 < K) v.x = p[0];
                if (kk + 1 < K) v.y = p[1];
                if (kk + 2 < K) v.z = p[2];
                if (kk + 3 < K) v.w = p[3];
            }
            As[kq * 4 + 0][m] = v.x; As[kq * 4 + 1][m] = v.y;
            As[kq * 4 + 2][m] = v.z; As[kq * 4 + 3][m] = v.w;
        }
        if (!wtrans) {
#pragma unroll
            for (int i = 0; i < 4; ++i) {
                int j = t + i * 64;
                int k = j >> 4, nq = j & 15;
                float4 v = {0.f, 0.f, 0.f, 0.f};
                if (k0 + k < K)
                    v = *(const float4*)(Wb + (long long)(k0 + k) * wld + n0 + nq * 4);
                *(float4*)&Ws[k][nq * 4] = v;
            }
        } else {
#pragma unroll
            for (int i = 0; i < 4; ++i) {
                int j = t + i * 64;
                int n = j >> 2, kq = j & 3;
                int kk = k0 + kq * 4;
                const float* p = Wb + (long long)(n0 + n) * wld + kk;
                float4 v = {0.f, 0.f, 0.f, 0.f};
                if (kk + 3 < K) v = *(const float4*)p;
                else {
                    if (kk + 0 < K) v.x = p[0];
                    if (kk + 1 < K) v.y = p[1];
                    if (kk + 2 < K) v.z = p[2];
                    if (kk + 3 < K) v.w = p[3];
                }
                Ws[kq * 4 + 0][n] = v.x; Ws[kq * 4 + 1][n] = v.y;
                Ws[kq * 4 + 2][n] = v.z; Ws[kq * 4 + 3][n] = v.w;
            }
        }
        __syncthreads();
#pragma unroll
        for (int k = 0; k < 16; ++k) {
            float4 a0 = *(const float4*)&As[k][ty * 8];
            float4 a1 = *(const float4*)&As[k][ty * 8 + 4];
            float4 b0 = *(const float4*)&Ws[k][tx * 8];
            float4 b1 = *(const float4*)&Ws[k][tx * 8 + 4];
            float av[8] = {a0.x, a0.y, a0.z, a0.w, a1.x, a1.y, a1.z, a1.w};
            float bv[8] = {b0.x, b0.y, b0.z, b0.w, b1.x, b1.y, b1.z, b1.w};
#pragma unroll
            for (int i = 0; i < 8; ++i)
#pragma unroll
                for (int j = 0; j < 8; ++j)
                    acc[i][j] = fmaf(av[i], bv[j], acc[i][j]);
        }
        __syncthreads();
    }

#pragma unroll
    for (int i = 0; i < 8; ++i) {
        long long gm = m0 + ty * 8 + i;
#pragma unroll
        for (int jq = 0; jq < 2; ++jq) {
            float* cp = Cb + gm * ldc + n0 + tx * 8 + jq * 4;
            float4 v;
            v.x = alpha * acc[i][jq * 4 + 0]; v.y = alpha * acc[i][jq * 4 + 1];
            v.z = alpha * acc[i][jq * 4 + 2]; v.w = alpha * acc[i][jq * 4 + 3];
            if (bb) {
                const float* bp = bb + n0 + tx * 8 + jq * 4;
                v.x += bp[0]; v.y += bp[1]; v.z += bp[2]; v.w += bp[3];
            }
            if (accum) {
                float4 o = *(const float4*)cp;
                v.x += o.x; v.y += o.y; v.z += o.z; v.w += o.w;
            }
            *(float4*)cp = v;
        }
    }
}

// ---------------- generic GEMM launcher-kernel ----------------
__global__ __launch_bounds__(64) void gemm_k(
    const float* __restrict__ A, long long a_z, int a_zdiv, int lda,
    const int* __restrict__ idx,
    const float* __restrict__ W, long long w_z, int wld, int wtrans,
    const float* __restrict__ bias, int bias_z,
    float* __restrict__ C, long long c_z, int ldc,
    int K, float alpha, int accum)
{
    int z = blockIdx.z;
    gemm_body(A + (long long)(z / a_zdiv) * a_z, lda, idx,
              W + (long long)z * w_z, wld, wtrans,
              bias ? bias + (long long)z * bias_z : nullptr,
              C + (long long)z * c_z, ldc, K, alpha, accum);
}

// ---------------- batched attention score: S[z] = scale * q_b @ kv_b^T ------
__global__ __launch_bounds__(64) void att_score_k(
    const float* __restrict__ X, float* __restrict__ S,
    int q0, int q1, int q2, int k0, int k1, int k2)
{
    int z = blockIdx.z;
    int pair = z >> 6, b = z & 63;
    int qi = pair == 0 ? q0 : (pair == 1 ? q1 : q2);
    int ki = pair == 0 ? k0 : (pair == 1 ? k1 : k2);
    gemm_body(X + (long long)qi * 2097152 + (long long)b * 32768, 128, nullptr,
              X + (long long)ki * 2097152 + (long long)b * 32768, 128, 1,
              nullptr,
              S + (long long)z * 65536, 256, 128, 0.08838834764831845f, 0);
}

// ---------------- batched attention apply: tstep_slice += P_b @ kv_b --------
__global__ __launch_bounds__(64) void att_apply_k(
    const float* __restrict__ S, const float* __restrict__ X,
    float* __restrict__ tstep,
    int q0, int q1, int q2, int k0, int k1, int k2)
{
    int z = blockIdx.z;
    int pair = z >> 6, b = z & 63;
    int qi = pair == 0 ? q0 : (pair == 1 ? q1 : q2);
    int ki = pair == 0 ? k0 : (pair == 1 ? k1 : k2);
    gemm_body(S + (long long)z * 65536, 256, nullptr,
              X + (long long)ki * 2097152 + (long long)b * 32768, 128, 0,
              nullptr,
              tstep + (long long)qi * 128 + (long long)b * 98304, 384,
              256, 1.f, 1);
}

// ---------------- tstep init ----------------
__global__ __launch_bounds__(256) void copy_tstep_k(const float* __restrict__ x,
                                                    float* __restrict__ tstep)
{
    int o = blockIdx.x * 256 + threadIdx.x;
    int c = o % 384;
    int row = o / 384;
    int m = c >> 7, cc = c & 127;
    tstep[o] = x[(long long)m * 2097152 + (long long)row * 128 + cc];
}

// ---------------- softmax over rows of 256 (one wave per row) ----------------
__global__ __launch_bounds__(256) void softmax_k(float* __restrict__ S)
{
    int wave = threadIdx.x >> 6, lane = threadIdx.x & 63;
    int row = blockIdx.x * 4 + wave;
    float* p = S + (long long)row * 256;
    float v[4];
    float mx = -1e30f;
#pragma unroll
    for (int i = 0; i < 4; ++i) { v[i] = p[lane + i * 64]; mx = fmaxf(mx, v[i]); }
#pragma unroll
    for (int off = 32; off > 0; off >>= 1) mx = fmaxf(mx, __shfl_xor(mx, off));
    float sum = 0.f;
#pragma unroll
    for (int i = 0; i < 4; ++i) { v[i] = __expf(v[i] - mx); sum += v[i]; }
#pragma unroll
    for (int off = 32; off > 0; off >>= 1) sum += __shfl_xor(sum, off);
    float inv = 1.f / sum;
#pragma unroll
    for (int i = 0; i < 4; ++i) p[lane + i * 64] = v[i] * inv;
}

// ---------------- GRU recurrence: 192 thr, 1 col/thread, 64 w in 4 vf16 ------
// Per-thread weight state = 64 floats -> fits any VGPR budget (no spill).
__global__ __launch_bounds__(192) void gru_rec_k(const float* __restrict__ xg,
                                                 const float* __restrict__ Wh,
                                                 const float* __restrict__ bh,
                                                 float* __restrict__ xout)
{
    int b = blockIdx.x, z = blockIdx.y;
    int m = z >> 1, d = z & 1;
    int tid = threadIdx.x, lane = tid & 63;
    int c = tid;                        // gate column 0..191
    const float* Whz = Wh + (long long)z * 12288;   // [64][192]
    const float* wp = Whz + c;
    vf16 W0, W1, W2, W3;
    LD16(W0, wp + 0 * 16 * 192, 192); LD16(W1, wp + 1 * 16 * 192, 192);
    LD16(W2, wp + 2 * 16 * 192, 192); LD16(W3, wp + 3 * 16 * 192, 192);
    float bias = bh[z * 192 + c];       // hidden bias folds into h-dot

    __shared__ float hs[64];
    __shared__ float g[192];
    int n = tid;                        // gate-thread col (tid<64)
    float h = 0.f;
    const float* xgb = xg + (long long)z * 3145728 + (long long)b * 49152;
    float* xob = xout + (long long)m * 2097152 + (long long)b * 32768 + d * 64;
    float x_r = 0, x_z = 0, x_n = 0;
    if (tid < 64) {
        hs[n] = 0.f;
        int tt0 = d ? 255 : 0;
        const float* xr = xgb + tt0 * 192;
        x_r = xr[n]; x_z = xr[64 + n]; x_n = xr[128 + n];
    }
    __syncthreads();

#pragma unroll 1
    for (int t = 0; t < 256; ++t) {
        int tt = d ? 255 - t : t;
        float nx_r = 0, nx_z = 0, nx_n = 0;
        if (tid < 64 && t < 255) {
            const float* xr = xgb + (d ? tt - 1 : tt + 1) * 192;
            nx_r = xr[n]; nx_z = xr[64 + n]; nx_n = xr[128 + n];
        }
        float hv = hs[lane];
        float s0 = bias, s1 = 0.f, s2 = 0.f, s3 = 0.f;
        DOT16(s0, W0, hv, 0);  DOT16(s1, W1, hv, 16);
        DOT16(s2, W2, hv, 32); DOT16(s3, W3, hv, 48);
        g[c] = (s0 + s1) + (s2 + s3);
        __syncthreads();
        if (tid < 64) {
            float r  = sigf(x_r + g[n]);
            float zz = sigf(x_z + g[64 + n]);
            float nn = tanhf(x_n + r * g[128 + n]);   // bh(n) inside r*(), x outside
            h = (1.f - zz) * nn + zz * h;
            hs[n] = h;
            xob[tt * 128 + n] = h;
            x_r = nx_r; x_z = nx_z; x_n = nx_n;
        }
        __syncthreads();
    }
}

// ---------------- LSTM recurrence: 1024 thr, K split in 2, 64 w/thread -------
__global__ __launch_bounds__(1024) void lstm_rec_k(const float* __restrict__ xg,
                                                   const float* __restrict__ Wh,
                                                   const float* __restrict__ bh,
                                                   float* __restrict__ sf)
{
    int b = blockIdx.x, d = blockIdx.y;
    int tid = threadIdx.x, lane = tid & 63;
    int kh = tid >> 9;                  // k-half 0/1 (wave-uniform: waves 0-7 / 8-15)
    int c  = tid & 511;                 // gate column
    const float* Whz = Wh + (long long)d * 65536;   // [128][512]
    const float* wp = Whz + (long long)(kh * 64) * 512 + c;
    vf16 W0, W1, W2, W3;
    LD16(W0, wp + 0 * 16 * 512, 512); LD16(W1, wp + 1 * 16 * 512, 512);
    LD16(W2, wp + 2 * 16 * 512, 512); LD16(W3, wp + 3 * 16 * 512, 512);

    __shared__ float hs[128];
    __shared__ float part[1024];
    int n = tid;                        // gate-thread col (tid<128)
    float b_i = 0, b_f = 0, b_g = 0, b_o = 0, h = 0.f, cst = 0.f;
    const float* xgb = xg + (long long)d * 8388608 + (long long)b * 131072;
    float* sfb = sf + (long long)b * 65536 + d * 128;
    float x_i = 0, x_f = 0, x_g = 0, x_o = 0;
    if (tid < 128) {
        b_i = bh[d * 512 + n];       b_f = bh[d * 512 + 128 + n];
        b_g = bh[d * 512 + 256 + n]; b_o = bh[d * 512 + 384 + n];
        hs[n] = 0.f;
        int tt0 = d ? 255 : 0;
        const float* xr = xgb + tt0 * 512;
        x_i = xr[n]; x_f = xr[128 + n]; x_g = xr[256 + n]; x_o = xr[384 + n];
    }
    __syncthreads();

#pragma unroll 1
    for (int t = 0; t < 256; ++t) {
        int tt = d ? 255 - t : t;
        float nx_i = 0, nx_f = 0, nx_g = 0, nx_o = 0;
        if (tid < 128 && t < 255) {
            const float* xr = xgb + (d ? tt - 1 : tt + 1) * 512;
            nx_i = xr[n]; nx_f = xr[128 + n]; nx_g = xr[256 + n]; nx_o = xr[384 + n];
        }
        float hv = hs[kh * 64 + lane];
        float s0 = 0.f, s1 = 0.f, s2 = 0.f, s3 = 0.f;
        DOT16(s0, W0, hv, 0);  DOT16(s1, W1, hv, 16);
        DOT16(s2, W2, hv, 32); DOT16(s3, W3, hv, 48);
        part[kh * 512 + c] = (s0 + s1) + (s2 + s3);
        __syncthreads();
        if (tid < 128) {
            float iv = part[n]       + part[512 + n]       + b_i + x_i;
            float fv = part[128 + n] + part[512 + 128 + n] + b_f + x_f;
            float gv = part[256 + n] + part[512 + 256 + n] + b_g + x_g;
            float ov = part[384 + n] + part[512 + 384 + n] + b_o + x_o;
            cst = sigf(fv) * cst + sigf(iv) * tanhf(gv);
            h = sigf(ov) * tanhf(cst);
            hs[n] = h;
            sfb[tt * 256 + n] = h;
            x_i = nx_i; x_f = nx_f; x_g = nx_g; x_o = nx_o;
        }
        __syncthreads();
    }
}

// ---------------- RGN recurrence: 768 thr, K split in 2, 64 w/thread ---------
__global__ __launch_bounds__(768) void rgn_rec_k(const float* __restrict__ xg,
                                                 const float* __restrict__ Wh,
                                                 const float* __restrict__ state0,
                                                 const float* __restrict__ state1,
                                                 float* __restrict__ outbase)
{
    int b = blockIdx.x, d = blockIdx.y;
    int tid = threadIdx.x, lane = tid & 63;
    int kh = (tid >= 384) ? 1 : 0;      // wave-uniform (384 = 6 waves)
    int c  = tid - kh * 384;            // gate column 0..383
    const float* Whz = Wh + (long long)d * 49152;   // [128][384]
    const float* wp = Whz + (long long)(kh * 64) * 384 + c;
    vf16 W0, W1, W2, W3;
    LD16(W0, wp + 0 * 16 * 384, 384); LD16(W1, wp + 1 * 16 * 384, 384);
    LD16(W2, wp + 2 * 16 * 384, 384); LD16(W3, wp + 3 * 16 * 384, 384);

    __shared__ float hs[128];
    __shared__ float part[768];
    int n = tid;                        // gate-thread col (tid<128)
    float h = 0.f;
    const float* st = d ? state1 : state0;
    const float* xgb = xg + (long long)d * 6291456 + (long long)b * 98304;
    float x_r = 0, x_z = 0, x_n = 0;
    if (tid < 128) {
        h = st[b * 128 + n];
        hs[n] = h;
        int tt0 = d ? 255 : 0;
        const float* xr = xgb + tt0 * 384;
        x_r = xr[n]; x_z = xr[128 + n]; x_n = xr[256 + n];
    }
    __syncthreads();

#pragma unroll 1
    for (int t = 0; t < 256; ++t) {
        int tt = d ? 255 - t : t;
        float nx_r = 0, nx_z = 0, nx_n = 0;
        if (tid < 128 && t < 255) {
            const float* xr = xgb + (d ? tt - 1 : tt + 1) * 384;
            nx_r = xr[n]; nx_z = xr[128 + n]; nx_n = xr[256 + n];
        }
        float hv = hs[kh * 64 + lane];
        float s0 = 0.f, s1 = 0.f, s2 = 0.f, s3 = 0.f;
        DOT16(s0, W0, hv, 0);  DOT16(s1, W1, hv, 16);
        DOT16(s2, W2, hv, 32); DOT16(s3, W3, hv, 48);
        part[kh * 384 + c] = (s0 + s1) + (s2 + s3);
        __syncthreads();
        if (tid < 128) {
            float pr = part[n]       + part[384 + n];
            float pz = part[128 + n] + part[384 + 128 + n];
            float pn = part[256 + n] + part[384 + 256 + n];
            float r  = sigf(x_r + pr);
            float zz = sigf(x_z + pz);
            float nn = tanhf(x_n + r * pn);       // RGN: no hidden bias
            h = (1.f - zz) * nn + zz * h;
            hs[n] = h;
            x_r = nx_r; x_z = nx_z; x_n = nx_n;
        }
        __syncthreads();
    }
    if (tid < 128) outbase[(long long)d * 8192 + b * 128 + n] = h;
}

// ---------------- final FC ----------------
__global__ __launch_bounds__(256) void fc_k(const float* __restrict__ o01,
                                            const float* __restrict__ f1W,
                                            const float* __restrict__ f1b,
                                            const float* __restrict__ f2W,
                                            const float* __restrict__ f2b,
                                            float* __restrict__ out)
{
    __shared__ float s[8192];
    __shared__ float h1[2048];
    int tid = threadIdx.x;
    for (int e = tid; e < 8192; e += 256) s[e] = o01[e] + o01[8192 + e];
    __syncthreads();
    for (int o = tid; o < 2048; o += 256) {
        int b = o >> 5, q = o & 31;
        float acc = f1b[q];
        for (int k = 0; k < 128; ++k) acc += s[b * 128 + k] * f1W[k * 32 + q];
        h1[o] = acc >= 0.f ? acc : 0.01f * acc;
    }
    __syncthreads();
    if (tid < 64) {
        float acc = f2b[0];
        for (int q = 0; q < 32; ++q) acc += h1[tid * 32 + q] * f2W[q];
        out[tid] = acc;
    }
}

// ============================ launch =========================================
extern "C" void kernel_launch(void* const* d_in, const int* in_sizes, int n_in,
                              void* d_out, int out_size, void* d_ws, size_t ws_size,
                              hipStream_t stream)
{
    const int*   sent     = (const int*)  d_in[0];
    const float* acoustic = (const float*)d_in[1];
    const float* video    = (const float*)d_in[2];
    const float* state0   = (const float*)d_in[3];
    const float* state1   = (const float*)d_in[4];
    const float* emb      = (const float*)d_in[5];
    const float* plW = (const float*)d_in[6],  *plb = (const float*)d_in[7];
    const float* paW = (const float*)d_in[8],  *pab = (const float*)d_in[9];
    const float* pvW = (const float*)d_in[10], *pvb = (const float*)d_in[11];
    const float* gWi = (const float*)d_in[12], *gWh = (const float*)d_in[13];
    const float* gbi = (const float*)d_in[14], *gbh = (const float*)d_in[15];
    const float* lWi = (const float*)d_in[16], *lWh = (const float*)d_in[17];
    const float* lbi = (const float*)d_in[18], *lbh = (const float*)d_in[19];
    const float* rWx = (const float*)d_in[20], *rWh = (const float*)d_in[21];
    const float* rb  = (const float*)d_in[22];
    const float* f1W = (const float*)d_in[23], *f1b = (const float*)d_in[24];
    const float* f2W = (const float*)d_in[25], *f2b = (const float*)d_in[26];
    float* ws  = (float*)d_ws;
    float* out = (float*)d_out;

    dim3 blk(64);

    // modality projections -> seq[3][16384][128]
    gemm_k<<<dim3(2, 256, 1), blk, 0, stream>>>(emb, 0, 1, 300, sent,
        plW, 0, 128, 0, plb, 0, ws + WS_SEQ, 0, 128, 300, 1.f, 0);
    gemm_k<<<dim3(2, 256, 1), blk, 0, stream>>>(acoustic, 0, 1, 74, nullptr,
        paW, 0, 128, 0, pab, 0, ws + WS_SEQ + 2097152, 0, 128, 74, 1.f, 0);
    gemm_k<<<dim3(2, 256, 1), blk, 0, stream>>>(video, 0, 1, 35, nullptr,
        pvW, 0, 128, 0, pvb, 0, ws + WS_SEQ + 4194304, 0, 128, 35, 1.f, 0);

    // GRU input projections, z = modality*2 + dir
    gemm_k<<<dim3(3, 256, 6), blk, 0, stream>>>(ws + WS_SEQ, 2097152, 2, 128, nullptr,
        gWi, 24576, 192, 0, gbi, 192, ws + WS_XGGRU, 3145728, 192, 128, 1.f, 0);

    // GRU recurrences -> x[3][16384][128]
    gru_rec_k<<<dim3(64, 6), dim3(192), 0, stream>>>(ws + WS_XGGRU, gWh, gbh, ws + WS_X);

    // tstep = concat(x_l, x_a, x_v)
    copy_tstep_k<<<dim3(24576), dim3(256), 0, stream>>>(ws + WS_X, ws + WS_TSTEP);

    // attention: two race-free rounds of 3 pairs (distinct q-modality per round)
    att_score_k<<<dim3(4, 4, 192), blk, 0, stream>>>(ws + WS_X, ws + WS_S,
        0, 1, 2, 1, 0, 0);
    softmax_k<<<dim3(12288), dim3(256), 0, stream>>>(ws + WS_S);
    att_apply_k<<<dim3(2, 4, 192), blk, 0, stream>>>(ws + WS_S, ws + WS_X,
        ws + WS_TSTEP, 0, 1, 2, 1, 0, 0);
    att_score_k<<<dim3(4, 4, 192), blk, 0, stream>>>(ws + WS_X, ws + WS_S,
        0, 1, 2, 2, 2, 1);
    softmax_k<<<dim3(12288), dim3(256), 0, stream>>>(ws + WS_S);
    att_apply_k<<<dim3(2, 4, 192), blk, 0, stream>>>(ws + WS_S, ws + WS_X,
        ws + WS_TSTEP, 0, 1, 2, 2, 2, 1);

    // LSTM input projections
    gemm_k<<<dim3(8, 256, 2), blk, 0, stream>>>(ws + WS_TSTEP, 0, 1, 384, nullptr,
        lWi, 196608, 512, 0, lbi, 512, ws + WS_XGLSTM, 8388608, 512, 384, 1.f, 0);

    // BiLSTM recurrences -> step_fusion[16384][256]
    lstm_rec_k<<<dim3(64, 2), dim3(1024), 0, stream>>>(ws + WS_XGLSTM, lWh, lbh, ws + WS_SF);

    // RGN input projections
    gemm_k<<<dim3(6, 256, 2), blk, 0, stream>>>(ws + WS_SF, 0, 1, 256, nullptr,
        rWx, 98304, 384, 0, rb, 384, ws + WS_XGRGN, 6291456, 384, 256, 1.f, 0);

    // RGN recurrences -> out0/out1 [64][128]
    rgn_rec_k<<<dim3(64, 2), dim3(768), 0, stream>>>(ws + WS_XGRGN, rWh, state0, state1,
                                                     ws + WS_OUT0);

    // final FC -> d_out [64]
    fc_k<<<dim3(1), dim3(256), 0, stream>>>(ws + WS_OUT0, f1W, f1b, f2W, f2b, out);
}